// Round 6
// baseline (89.335 us; speedup 1.0000x reference)
//
#include <hip/hip_runtime.h>
#include <math.h>

#define T 512
#define NCH 32
#define BATCH 16
#define DM 512

// ---------------------------------------------------------------------------
// Kernel A: two-stage DFT (8 x 64 decimation) per (b,n), with real-input
// conjugate symmetry: Z_v[64-j] = conj(Z_v[j]) -> only j=0..32 computed.
// flags[b*32+n] = 1 iff Nyquist bin strictly beats bins 0..255.
// ---------------------------------------------------------------------------
__global__ __launch_bounds__(256) void dft2_kernel(const float* __restrict__ x,
                                                   int* __restrict__ flags) {
    __shared__ float  xv[T];        // xv[v*64+u] = x[8u+v]
    __shared__ float2 zs[T];        // zs[v*64+j] = Z_v[j]
    __shared__ float  s_mag[256];

    const int tid = threadIdx.x;
    const int b   = blockIdx.x >> 5;
    const int n   = blockIdx.x & 31;

    for (int t = tid; t < T; t += 256) {
        float val = x[(b * T + t) * NCH + n];
        xv[(t & 7) * 64 + (t >> 3)] = val;
    }
    __syncthreads();

    const int v = tid >> 5;
    const int j = tid & 31;
    float sd, cd;
    sincospif(-(float)j * (1.0f / 32.0f), &sd, &cd);   // e^{-2pi i j/64}

    {
        const float4* xp = (const float4*)&xv[v * 64];
        float wr = 1.0f, wi = 0.0f, zr = 0.0f, zi = 0.0f, alt = 0.0f;
        #pragma unroll 4
        for (int g = 0; g < 16; ++g) {
            float4 c = xp[g];    // wave-uniform broadcast b128
            alt += (c.x + c.z) - (c.y + c.w);
            zr = fmaf(c.x, wr, zr); zi = fmaf(c.x, wi, zi);
            { float nr = fmaf(wr, cd, -(wi * sd)); float ni = fmaf(wr, sd, wi * cd); wr = nr; wi = ni; }
            zr = fmaf(c.y, wr, zr); zi = fmaf(c.y, wi, zi);
            { float nr = fmaf(wr, cd, -(wi * sd)); float ni = fmaf(wr, sd, wi * cd); wr = nr; wi = ni; }
            zr = fmaf(c.z, wr, zr); zi = fmaf(c.z, wi, zi);
            { float nr = fmaf(wr, cd, -(wi * sd)); float ni = fmaf(wr, sd, wi * cd); wr = nr; wi = ni; }
            zr = fmaf(c.w, wr, zr); zi = fmaf(c.w, wi, zi);
            { float nr = fmaf(wr, cd, -(wi * sd)); float ni = fmaf(wr, sd, wi * cd); wr = nr; wi = ni; }
        }
        zs[v * 64 + j] = make_float2(zr, zi);
        zs[v * 64 + ((64 - j) & 63)] = make_float2(zr, -zi);   // conj mirror
        if (j == 0) zs[v * 64 + 32] = make_float2(alt, 0.0f);  // Z_v[32]
    }
    __syncthreads();

    const int j2 = tid & 63;
    float s2, c2;
    sincospif(-(float)tid * (1.0f / 256.0f), &s2, &c2); // e^{-2pi i k/512}
    float tr = 1.0f, ti = 0.0f, ar = 0.0f, ai = 0.0f;
    #pragma unroll
    for (int vv = 0; vv < 8; ++vv) {
        float2 z = zs[vv * 64 + j2];
        ar = fmaf(tr, z.x, ar); ar = fmaf(-ti, z.y, ar);
        ai = fmaf(tr, z.y, ai); ai = fmaf(ti, z.x, ai);
        float nr = fmaf(tr, c2, -(ti * s2));
        float ni = fmaf(tr, s2, ti * c2);
        tr = nr; ti = ni;
    }
    s_mag[tid] = ar * ar + ai * ai;
    __syncthreads();

    for (int s2r = 128; s2r > 0; s2r >>= 1) {
        if (tid < s2r) s_mag[tid] = fmaxf(s_mag[tid], s_mag[tid + s2r]);
        __syncthreads();
    }
    if (tid == 0) {
        float ny = zs[0].x - zs[64].x + zs[128].x - zs[192].x +
                   zs[256].x - zs[320].x + zs[384].x - zs[448].x;
        flags[blockIdx.x] = (ny * ny > s_mag[0]) ? 1 : 0;  // unconditional
    }
}

// ---------------------------------------------------------------------------
// Kernel B: fused conv1d(circular,k=3) + temporal + cycle embedding.
// grid (32 t-chunks, 16 b, 2 d-halves) x 256 threads, one d-column/thread.
// Conv rows and xmark read DIRECTLY from global with block-uniform addresses
// -> compiler emits scalar s_load into SGPRs; no LDS staging for x at all.
// LDS holds only the 7x256 temporal table.
// ---------------------------------------------------------------------------
__global__ __launch_bounds__(256, 3) void fused4_kernel(const float* __restrict__ x,
                                                        const int*   __restrict__ xmark,
                                                        const float* __restrict__ conv_w,
                                                        const int*   __restrict__ flags,
                                                        float*       __restrict__ out) {
    __shared__ float ttbl[7 * 256];    // temporal table rows p=0..6, this d-half
    __shared__ int   s_kb;

    const int tid = threadIdx.x;
    const int t0  = blockIdx.x * 16;
    const int b   = blockIdx.y;
    const int d   = blockIdx.z * 256 + tid;

    // reduce this batch's 32 Nyquist flags (wave 0 only)
    if (tid < 64) {
        int f = (tid < 32) ? flags[b * 32 + tid] : 0;
        f += __shfl_down(f, 32);
        f += __shfl_down(f, 16);
        f += __shfl_down(f, 8);
        f += __shfl_down(f, 4);
        f += __shfl_down(f, 2);
        f += __shfl_down(f, 1);
        if (tid == 0) s_kb = f;
    }

    // conv weights -> 96 registers
    float w[96];
    {
        const float4* wp = (const float4*)(conv_w + d * 96);
        #pragma unroll
        for (int i = 0; i < 24; ++i) {
            float4 v0 = wp[i];
            w[4*i+0] = v0.x; w[4*i+1] = v0.y; w[4*i+2] = v0.z; w[4*i+3] = v0.w;
        }
    }

    // fixed-embedding generator: f(p,d) = sin(p*dv + (d&1)*pi/2)
    const bool  odd = (d & 1);
    const float dv  = expf((float)(d & ~1) * (-9.210340371976184f / 512.0f));
    float sd_, cd_;
    sincosf(dv, &sd_, &cd_);

    // temporal table rows 0..6 for this column (rotation from phi=0)
    {
        float s = 0.0f, c = 1.0f;
        #pragma unroll
        for (int p = 0; p < 7; ++p) {
            ttbl[p * 256 + tid] = odd ? c : s;
            float ns = fmaf(c, sd_, s * cd_);
            float nc = fmaf(c, cd_, -(s * sd_));
            s = ns; c = nc;
        }
    }

    // running sin/cos of t*dv starting at t0
    float st, ct;
    sincosf((float)t0 * dv, &st, &ct);

    __syncthreads();

    const float f0   = odd ? 1.0f : 0.0f;
    const int   kb   = s_kb;
    const float wt   = (float)(32 - kb) * (1.0f / 32.0f);
    const float wkf0 = (float)kb * (1.0f / 32.0f) * f0;

    const float* xb = x + (size_t)b * T * NCH;

    // pipeline partials: A0=output r (tap 0), A1=output r-1, A2=output r-2
    float A0 = 0.0f, A1 = 0.0f, A2 = 0.0f;

    #pragma unroll 2
    for (int r = 0; r < 18; ++r) {
        const int t = (t0 + r - 1) & (T - 1);
        const float4* rowp = (const float4*)(xb + t * NCH);   // block-uniform -> s_load
        A0 = 0.0f;
        #pragma unroll
        for (int q = 0; q < 8; ++q) {
            float4 c = rowp[q];
            const int w0 = 12 * q;
            A0 = fmaf(c.x, w[w0+0], A0); A1 = fmaf(c.x, w[w0+1],  A1); A2 = fmaf(c.x, w[w0+2],  A2);
            A0 = fmaf(c.y, w[w0+3], A0); A1 = fmaf(c.y, w[w0+4],  A1); A2 = fmaf(c.y, w[w0+5],  A2);
            A0 = fmaf(c.z, w[w0+6], A0); A1 = fmaf(c.z, w[w0+7],  A1); A2 = fmaf(c.z, w[w0+8],  A2);
            A0 = fmaf(c.w, w[w0+9], A0); A1 = fmaf(c.w, w[w0+10], A1); A2 = fmaf(c.w, w[w0+11], A2);
        }
        if (r >= 2) {
            const int tt = t0 + r - 2;
            const int4 smv = *(const int4*)(xmark + ((size_t)b * T + tt) * 4);  // uniform -> s_load
            float temp = ttbl[smv.x * 256 + tid] + ttbl[smv.y * 256 + tid] +
                         ttbl[smv.z * 256 + tid] + ttbl[smv.w * 256 + tid];
            float ft = odd ? ct : st;
            out[((size_t)b * T + tt) * DM + d] = A2 + temp + fmaf(wt, ft, wkf0);
            // rotate running sin/cos by dv
            float ns = fmaf(ct, sd_, st * cd_);
            float nc = fmaf(ct, cd_, -(st * sd_));
            st = ns; ct = nc;
        }
        // shift pipeline
        A2 = A1; A1 = A0;
    }
}

extern "C" void kernel_launch(void* const* d_in, const int* in_sizes, int n_in,
                              void* d_out, int out_size, void* d_ws, size_t ws_size,
                              hipStream_t stream) {
    const float* x      = (const float*)d_in[0];
    const int*   xmark  = (const int*)d_in[1];
    const float* conv_w = (const float*)d_in[2];
    float*       out    = (float*)d_out;
    int*         flags  = (int*)d_ws;

    dft2_kernel<<<dim3(BATCH * NCH), dim3(256), 0, stream>>>(x, flags);
    fused4_kernel<<<dim3(T / 16, BATCH, 2), dim3(256), 0, stream>>>(x, xmark, conv_w, flags, out);
}

// Round 7
// 86.553 us; speedup vs baseline: 1.0321x; 1.0321x over previous
//
#include <hip/hip_runtime.h>
#include <math.h>

#define T 512
#define NCH 32
#define BATCH 16
#define DM 512

// ---------------------------------------------------------------------------
// Kernel A: two-stage DFT (8 x 64 decimation) per (b,n), with real-input
// conjugate symmetry: Z_v[64-j] = conj(Z_v[j]) -> only j=0..32 computed.
// Writes flags[b*32+n] = 1 iff Nyquist bin strictly beats bins 0..255
// (non-Nyquist bins clamp to period 512 -> pidx=t; Nyquist -> pidx=0).
// Unconditional write => no memset of d_ws needed (poison-safe).
// ---------------------------------------------------------------------------
__global__ __launch_bounds__(256) void dft2_kernel(const float* __restrict__ x,
                                                   int* __restrict__ flags) {
    __shared__ float  xv[T];        // xv[v*64+u] = x[8u+v]
    __shared__ float2 zs[T];        // zs[v*64+j] = Z_v[j]
    __shared__ float  s_mag[256];

    const int tid = threadIdx.x;
    const int b   = blockIdx.x >> 5;
    const int n   = blockIdx.x & 31;

    // stage + transpose
    for (int t = tid; t < T; t += 256) {
        float val = x[(b * T + t) * NCH + n];
        xv[(t & 7) * 64 + (t >> 3)] = val;
    }
    __syncthreads();

    // ---- stage 1: thread (v = tid>>5, j = tid&31) computes Z_v[j] ----
    const int v = tid >> 5;
    const int j = tid & 31;
    float sd, cd;
    sincospif(-(float)j * (1.0f / 32.0f), &sd, &cd);   // e^{-2pi i j/64}

    {
        const float4* xp = (const float4*)&xv[v * 64];
        float wr = 1.0f, wi = 0.0f, zr = 0.0f, zi = 0.0f, alt = 0.0f;
        #pragma unroll 4
        for (int g = 0; g < 16; ++g) {
            float4 c = xp[g];    // wave-uniform broadcast b128
            alt += (c.x + c.z) - (c.y + c.w);
            zr = fmaf(c.x, wr, zr); zi = fmaf(c.x, wi, zi);
            { float nr = fmaf(wr, cd, -(wi * sd)); float ni = fmaf(wr, sd, wi * cd); wr = nr; wi = ni; }
            zr = fmaf(c.y, wr, zr); zi = fmaf(c.y, wi, zi);
            { float nr = fmaf(wr, cd, -(wi * sd)); float ni = fmaf(wr, sd, wi * cd); wr = nr; wi = ni; }
            zr = fmaf(c.z, wr, zr); zi = fmaf(c.z, wi, zi);
            { float nr = fmaf(wr, cd, -(wi * sd)); float ni = fmaf(wr, sd, wi * cd); wr = nr; wi = ni; }
            zr = fmaf(c.w, wr, zr); zi = fmaf(c.w, wi, zi);
            { float nr = fmaf(wr, cd, -(wi * sd)); float ni = fmaf(wr, sd, wi * cd); wr = nr; wi = ni; }
        }
        zs[v * 64 + j] = make_float2(zr, zi);
        zs[v * 64 + ((64 - j) & 63)] = make_float2(zr, -zi);   // conj mirror
        if (j == 0) zs[v * 64 + 32] = make_float2(alt, 0.0f);  // Z_v[32]
    }
    __syncthreads();

    // ---- stage 2: X[k] = sum_v e^{-2*pi*i*k*v/512} * Z_v[k&63], k = tid ----
    const int j2 = tid & 63;
    float s2, c2;
    sincospif(-(float)tid * (1.0f / 256.0f), &s2, &c2); // e^{-2pi i k/512}
    float tr = 1.0f, ti = 0.0f, ar = 0.0f, ai = 0.0f;
    #pragma unroll
    for (int vv = 0; vv < 8; ++vv) {
        float2 z = zs[vv * 64 + j2];
        ar = fmaf(tr, z.x, ar); ar = fmaf(-ti, z.y, ar);
        ai = fmaf(tr, z.y, ai); ai = fmaf(ti, z.x, ai);
        float nr = fmaf(tr, c2, -(ti * s2));
        float ni = fmaf(tr, s2, ti * c2);
        tr = nr; ti = ni;
    }
    s_mag[tid] = ar * ar + ai * ai;
    __syncthreads();

    for (int s2r = 128; s2r > 0; s2r >>= 1) {
        if (tid < s2r) s_mag[tid] = fmaxf(s_mag[tid], s_mag[tid + s2r]);
        __syncthreads();
    }
    if (tid == 0) {
        // Nyquist: X[256] = sum_v (-1)^v * Z_v[0]  (purely real)
        float ny = zs[0].x - zs[64].x + zs[128].x - zs[192].x +
                   zs[256].x - zs[320].x + zs[384].x - zs[448].x;
        flags[blockIdx.x] = (ny * ny > s_mag[0]) ? 1 : 0;  // unconditional
    }
}

// ---------------------------------------------------------------------------
// Kernel B: fused conv1d(circular,k=3) + temporal + cycle embedding.
// grid (16 t-chunks, 16 b, 2 d-halves) x 256 threads, ONE d-column/thread.
// 512 blocks -> 2 blocks/CU -> 2 waves/SIMD (latency hiding).
// Row-pipelined sliding window: each xs row chunk is read from LDS ONCE,
// as wave-uniform broadcast ds_read_b128 (the right CDNA idiom; direct
// global reads of uniform addresses do NOT scalarize -> R6 regression).
// ---------------------------------------------------------------------------
__global__ __launch_bounds__(256) void fused3_kernel(const float* __restrict__ x,
                                                     const int*   __restrict__ xmark,
                                                     const float* __restrict__ conv_w,
                                                     const int*   __restrict__ flags,
                                                     float*       __restrict__ out) {
    __shared__ float xs[34 * NCH];     // rows t0-1 .. t0+32 (wrapped)
    __shared__ int   sm[32 * 4];
    __shared__ float ttbl[7 * 256];    // temporal table rows p=0..6, this d-half
    __shared__ int   s_kb;

    const int tid = threadIdx.x;
    const int t0  = blockIdx.x * 32;
    const int b   = blockIdx.y;
    const int d   = blockIdx.z * 256 + tid;

    // reduce this batch's 32 Nyquist flags (wave 0 only)
    if (tid < 64) {
        int f = (tid < 32) ? flags[b * 32 + tid] : 0;
        f += __shfl_down(f, 32);
        f += __shfl_down(f, 16);
        f += __shfl_down(f, 8);
        f += __shfl_down(f, 4);
        f += __shfl_down(f, 2);
        f += __shfl_down(f, 1);
        if (tid == 0) s_kb = f;
    }

    // conv weights -> 96 registers (issue loads early)
    float w[96];
    {
        const float4* wp = (const float4*)(conv_w + d * 96);
        #pragma unroll
        for (int i = 0; i < 24; ++i) {
            float4 v0 = wp[i];
            w[4*i+0] = v0.x; w[4*i+1] = v0.y; w[4*i+2] = v0.z; w[4*i+3] = v0.w;
        }
    }

    // stage x slab
    for (int i = tid; i < 34 * NCH; i += 256) {
        int row = i >> 5, n = i & 31;
        int t = (t0 + row - 1 + T) & (T - 1);
        xs[i] = x[(b * T + t) * NCH + n];
    }
    if (tid < 128) sm[tid] = xmark[(b * T + t0) * 4 + tid];

    // fixed-embedding generator: f(p,d) = sin(p*dv + (d&1)*pi/2)
    const bool  odd = (d & 1);
    const float dv  = expf((float)(d & ~1) * (-9.210340371976184f / 512.0f));
    float sd_, cd_;
    sincosf(dv, &sd_, &cd_);

    // temporal table rows 0..6 for this column (rotation from phi=0)
    {
        float s = 0.0f, c = 1.0f;
        #pragma unroll
        for (int p = 0; p < 7; ++p) {
            ttbl[p * 256 + tid] = odd ? c : s;
            float ns = fmaf(c, sd_, s * cd_);
            float nc = fmaf(c, cd_, -(s * sd_));
            s = ns; c = nc;
        }
    }

    // running sin/cos of t*dv starting at t0 (first emitted output)
    float st, ct;
    sincosf((float)t0 * dv, &st, &ct);

    __syncthreads();

    const float f0   = odd ? 1.0f : 0.0f;
    const int   kb   = s_kb;
    const float wt   = (float)(32 - kb) * (1.0f / 32.0f);
    const float wkf0 = (float)kb * (1.0f / 32.0f) * f0;

    // pipeline partials: A0=output r (tap 0), A1=output r-1 (tap 1), A2=output r-2 (tap 2)
    float A0 = 0.0f, A1 = 0.0f, A2 = 0.0f;

    #pragma unroll 2
    for (int r = 0; r < 34; ++r) {
        const float4* rowp = (const float4*)&xs[r * NCH];
        A0 = 0.0f;
        #pragma unroll
        for (int q = 0; q < 8; ++q) {
            float4 c = rowp[q];     // wave-uniform broadcast b128
            const int w0 = 12 * q;
            A0 = fmaf(c.x, w[w0+0], A0); A1 = fmaf(c.x, w[w0+1],  A1); A2 = fmaf(c.x, w[w0+2],  A2);
            A0 = fmaf(c.y, w[w0+3], A0); A1 = fmaf(c.y, w[w0+4],  A1); A2 = fmaf(c.y, w[w0+5],  A2);
            A0 = fmaf(c.z, w[w0+6], A0); A1 = fmaf(c.z, w[w0+7],  A1); A2 = fmaf(c.z, w[w0+8],  A2);
            A0 = fmaf(c.w, w[w0+9], A0); A1 = fmaf(c.w, w[w0+10], A1); A2 = fmaf(c.w, w[w0+11], A2);
        }
        if (r >= 2) {
            const int tt = r - 2;
            int4 smv = *(const int4*)&sm[tt * 4];   // wave-uniform broadcast
            float temp = ttbl[smv.x * 256 + tid] + ttbl[smv.y * 256 + tid] +
                         ttbl[smv.z * 256 + tid] + ttbl[smv.w * 256 + tid];
            float ft = odd ? ct : st;
            out[((size_t)(b * T) + t0 + tt) * DM + d] = A2 + temp + fmaf(wt, ft, wkf0);
            // rotate running sin/cos by dv
            float ns = fmaf(ct, sd_, st * cd_);
            float nc = fmaf(ct, cd_, -(st * sd_));
            st = ns; ct = nc;
        }
        // shift pipeline
        A2 = A1; A1 = A0;
    }
}

extern "C" void kernel_launch(void* const* d_in, const int* in_sizes, int n_in,
                              void* d_out, int out_size, void* d_ws, size_t ws_size,
                              hipStream_t stream) {
    const float* x      = (const float*)d_in[0];
    const int*   xmark  = (const int*)d_in[1];
    const float* conv_w = (const float*)d_in[2];
    float*       out    = (float*)d_out;
    int*         flags  = (int*)d_ws;

    dft2_kernel<<<dim3(BATCH * NCH), dim3(256), 0, stream>>>(x, flags);
    fused3_kernel<<<dim3(T / 32, BATCH, 2), dim3(256), 0, stream>>>(x, xmark, conv_w, flags, out);
}